// Round 2
// baseline (552.792 us; speedup 1.0000x reference)
//
#include <hip/hip_runtime.h>
#include <cmath>

#define BATCH 256
#define PAIRS 90
#define NPAIR (BATCH * PAIRS)
#define CV 1024

// Monotone float->uint key so unsigned atomicMax == float max.
__device__ __forceinline__ unsigned fkey(float f) {
    unsigned u = __float_as_uint(f);
    return (u & 0x80000000u) ? ~u : (u | 0x80000000u);
}
__device__ __forceinline__ float finv(unsigned k) {
    unsigned u = (k & 0x80000000u) ? (k & 0x7FFFFFFFu) : ~k;
    return __uint_as_float(u);
}

// K1: per pair (b,p): 8x8 adaptive max pool of 64x64 tile + attention score.
// 23040 blocks x 256 threads. Coalesced float4 loads (16KB/block).
__global__ __launch_bounds__(256) void pool_score_kernel(
    const float* __restrict__ feat, const float* __restrict__ w_att,
    const float* __restrict__ b_att, float* __restrict__ pooled,
    float* __restrict__ scores)
{
    const int pair = blockIdx.x;
    const float4* __restrict__ src = (const float4*)(feat + (size_t)pair * 4096);
    __shared__ unsigned smax[64];
    const int t = threadIdx.x;
    if (t < 64) smax[t] = 0u;  // below every real float's key
    __syncthreads();
#pragma unroll
    for (int i = 0; i < 4; ++i) {
        const int g = i * 256 + t;          // float4 index within tile (0..1023)
        float4 v = src[g];
        float m = fmaxf(fmaxf(v.x, v.y), fmaxf(v.z, v.w));
        const int row  = g >> 4;            // 16 float4 per 64-float row
        const int col4 = g & 15;
        const int w = ((row >> 3) << 3) + (col4 >> 1);  // fx*8 + fy
        atomicMax(&smax[w], fkey(m));
    }
    __syncthreads();
    if (t < 64) {  // wave 0 exactly
        float v = finv(smax[t]);
        pooled[(size_t)pair * 64 + t] = v;
        float part = v * w_att[t];
#pragma unroll
        for (int off = 32; off > 0; off >>= 1)
            part += __shfl_xor(part, off, 64);
        if (t == 0) scores[pair] = part + b_att[0];
    }
}

// K2: per batch top-k (k from device scalar), lowest-index tie-break (matches
// jax.lax.top_k). scale[b,p] = score if selected else 0.
__global__ __launch_bounds__(64) void topk_kernel(
    const float* __restrict__ scores, const int* __restrict__ kp,
    float* __restrict__ scale)
{
    const int b = blockIdx.x;
    const int l = threadIdx.x;       // one wave
    const int k = *kp;
    const int i0 = l, i1 = l + 64;
    const float s0 = (i0 < PAIRS) ? scores[b * PAIRS + i0] : -INFINITY;
    const float s1 = (i1 < PAIRS) ? scores[b * PAIRS + i1] : -INFINITY;
    float v0 = s0, v1 = s1;
    bool sel0 = false, sel1 = false;
    for (int it = 0; it < k && it < PAIRS; ++it) {
        float mv; int mi;
        if (v0 >= v1) { mv = v0; mi = i0; } else { mv = v1; mi = i1; }
#pragma unroll
        for (int off = 32; off > 0; off >>= 1) {
            float ov = __shfl_xor(mv, off, 64);
            int   oi = __shfl_xor(mi, off, 64);
            if (ov > mv || (ov == mv && oi < mi)) { mv = ov; mi = oi; }
        }
        if (mi == i0)      { sel0 = true; v0 = -INFINITY; }
        else if (mi == i1) { sel1 = true; v1 = -INFINITY; }
    }
    if (i0 < PAIRS) scale[b * PAIRS + i0] = sel0 ? s0 : 0.0f;
    if (i1 < PAIRS) scale[b * PAIRS + i1] = sel1 ? s1 : 0.0f;
}

// K3: out[row] = (pooled[row]*scale[row]) @ w_fc + b_fc. scale==0 rows (80/90)
// just broadcast b_fc. One block per row, thread t owns float4 j=t.
__global__ __launch_bounds__(256) void fc_kernel(
    const float* __restrict__ pooled, const float* __restrict__ scale,
    const float* __restrict__ w_fc, const float* __restrict__ b_fc,
    float* __restrict__ out)
{
    const int row = blockIdx.x;
    const int t = threadIdx.x;
    const float s = scale[row];                  // block-uniform
    float4* __restrict__ o = (float4*)(out + (size_t)row * CV);
    const float4* __restrict__ b4 = (const float4*)b_fc;
    if (s == 0.0f) {
        o[t] = b4[t];
        return;
    }
    __shared__ float sp[64];
    if (t < 64) sp[t] = pooled[(size_t)row * 64 + t] * s;
    __syncthreads();
    const float4* __restrict__ w4 = (const float4*)w_fc;
    float4 acc = b4[t];
#pragma unroll 8
    for (int i = 0; i < 64; ++i) {
        const float4 w = w4[i * 256 + t];
        const float c = sp[i];
        acc.x = fmaf(c, w.x, acc.x);
        acc.y = fmaf(c, w.y, acc.y);
        acc.z = fmaf(c, w.z, acc.z);
        acc.w = fmaf(c, w.w, acc.w);
    }
    o[t] = acc;
}

extern "C" void kernel_launch(void* const* d_in, const int* in_sizes, int n_in,
                              void* d_out, int out_size, void* d_ws, size_t ws_size,
                              hipStream_t stream) {
    const float* feat  = (const float*)d_in[0];
    const float* w_att = (const float*)d_in[1];
    const float* b_att = (const float*)d_in[2];
    const float* w_fc  = (const float*)d_in[3];
    const float* b_fc  = (const float*)d_in[4];
    const int*   kp    = (const int*)d_in[5];
    float* out = (float*)d_out;

    float* pooled = (float*)d_ws;                     // NPAIR*64 floats (5.9 MB)
    float* scores = pooled + (size_t)NPAIR * 64;      // NPAIR floats
    float* scale  = scores + NPAIR;                   // NPAIR floats

    hipLaunchKernelGGL(pool_score_kernel, dim3(NPAIR), dim3(256), 0, stream,
                       feat, w_att, b_att, pooled, scores);
    hipLaunchKernelGGL(topk_kernel, dim3(BATCH), dim3(64), 0, stream,
                       scores, kp, scale);
    hipLaunchKernelGGL(fc_kernel, dim3(NPAIR), dim3(256), 0, stream,
                       pooled, scale, w_fc, b_fc, out);
}